// Round 11
// baseline (263.572 us; speedup 1.0000x reference)
//
#include <hip/hip_runtime.h>
#include <hip/hip_bf16.h>

// EnhancedReprogrammingLayer: Q/K/V projections (bf16 MFMA), fused flash
// cross-attention over S=1000 prototypes, output projection to 4096.
// B=8, L=1024, H=8, E=128, D_MODEL=1024, D_LLM=4096, dk=1024.
//
// R1: split-K K/V proj. R2: LDS-free attn (swapped QK^T). R3: gemm_bb.
// R4/R5: 16 rows/wave LDS-free FAILED (per-wave K/V traffic). R6: LDS-staged
// dbuf attn, 32 rows/wave. R7: gemm256 counted-vmcnt 85.9us. R8 FAILED
// (2-phase barriers). R9 NEUTRAL (attn pipeline). R10: split-K on
// global_load_lds (251us).
// R11: attn = chain-latency bound at 2 waves/SIMD. The untested combo:
//      16 q-rows/wave + LDS staging (R4's parallelism without R5's traffic).
//      1024 blocks (4/CU, LDS 37.9KB*4=151.6KB), launch_bounds(256,4),
//      head->XCD decode (blockIdx&7=h) for L2 locality.

typedef __attribute__((ext_vector_type(8))) short short8;
typedef __attribute__((ext_vector_type(4))) short short4v;
typedef __attribute__((ext_vector_type(4))) float f32x4;
typedef __attribute__((ext_vector_type(4))) int int4v;

#define DEVINL static __device__ __forceinline__

DEVINL unsigned short f2bf(float f) {
  union { float f; unsigned u; } v; v.f = f;
  unsigned r = v.u + 0x7FFFu + ((v.u >> 16) & 1u);
  return (unsigned short)(r >> 16);
}

DEVINL f32x4 zero4() { f32x4 z; z[0] = 0.f; z[1] = 0.f; z[2] = 0.f; z[3] = 0.f; return z; }
DEVINL short8 zero8() { short8 z; z[0]=0; z[1]=0; z[2]=0; z[3]=0; z[4]=0; z[5]=0; z[6]=0; z[7]=0; return z; }

DEVINL void load_lds16(const unsigned short* g, unsigned short* l) {
  __builtin_amdgcn_global_load_lds(
      (const __attribute__((address_space(1))) void*)g,
      (__attribute__((address_space(3))) void*)l, 16, 0, 0);
}

// Bulk fp32 -> bf16 conversion for 3 buffers (8 elems/thread).
__global__ __launch_bounds__(256)
void cvt3_bf16(const float* __restrict__ s0, unsigned short* __restrict__ d0, int n0,
               const float* __restrict__ s1, unsigned short* __restrict__ d1, int n1,
               const float* __restrict__ s2, unsigned short* __restrict__ d2, int n2)
{
  int idx = (blockIdx.x * 256 + threadIdx.x) * 8;
  const float* s; unsigned short* d; int rel = idx;
  if (rel < n0) { s = s0; d = d0; }
  else {
    rel -= n0;
    if (rel < n1) { s = s1; d = d1; }
    else { rel -= n1; if (rel >= n2) return; s = s2; d = d2; }
  }
  f32x4 x0 = *(const f32x4*)(s + rel);
  f32x4 x1 = *(const f32x4*)(s + rel + 4);
  short8 o;
#pragma unroll
  for (int j = 0; j < 4; j++) { o[j] = (short)f2bf(x0[j]); o[4 + j] = (short)f2bf(x1[j]); }
  *(short8*)(d + rel) = o;
}

// Convert source/value (1000x4096, zero-padded to 1024 rows) and Wk/Wv
// (1024x4096) to bf16. 4 segments x 4,194,304 elems, 2048 blocks each.
__global__ __launch_bounds__(256)
void cvt_kv(const float* __restrict__ src, const float* __restrict__ val,
            const float* __restrict__ wk, const float* __restrict__ wv,
            unsigned short* __restrict__ Sb, unsigned short* __restrict__ Vb,
            unsigned short* __restrict__ Wkb, unsigned short* __restrict__ Wvb)
{
  const int seg = blockIdx.x >> 11;  // 2048 blocks per segment
  const int e = (((blockIdx.x & 2047) * 256) + threadIdx.x) * 8;
  const float* s;
  unsigned short* d;
  bool pad = false;
  if (seg == 0)      { s = src; d = Sb;  pad = (e >> 12) >= 1000; }
  else if (seg == 1) { s = val; d = Vb;  pad = (e >> 12) >= 1000; }
  else if (seg == 2) { s = wk;  d = Wkb; }
  else               { s = wv;  d = Wvb; }
  short8 o;
  if (pad) {
    o = zero8();
  } else {
    f32x4 x0 = *(const f32x4*)(s + e);
    f32x4 x1 = *(const f32x4*)(s + e + 4);
#pragma unroll
    for (int j = 0; j < 4; j++) { o[j] = (short)f2bf(x0[j]); o[4 + j] = (short)f2bf(x1[j]); }
  }
  *(short8*)(d + e) = o;
}

// ---------------- gemm256: 256x256 tile, BK=32, counted-vmcnt (R7) ----
__global__ __launch_bounds__(512, 2)
void gemm256(const unsigned short* __restrict__ A,
             const unsigned short* __restrict__ B,
             const float* __restrict__ bias, float cscale,
             float* __restrict__ C, int M, int N, int K)
{
  __shared__ unsigned short lds[49152];  // 96 KB
  const int tid = threadIdx.x;
  const int lane = tid & 63, w = tid >> 6;
  const int wr = w >> 2, wc = w & 3;
  const int l15 = lane & 15, l4 = lane >> 4;

  const int nwg = gridDim.x;
  const int q8 = nwg >> 3;
  const int swz = (blockIdx.x & 7) * q8 + (blockIdx.x >> 3);
  const int nbx = N >> 8;
  const int bx = swz % nbx, by = swz / nbx;
  const int m0 = by << 8, n0 = bx << 8;

  const unsigned short* gA[2];
  const unsigned short* gB[2];
#pragma unroll
  for (int i = 0; i < 2; i++) {
    const int c = i * 512 + tid;
    const int row = 2 * (c >> 3) + ((c >> 2) & 1);
    const int k4 = (c & 3) ^ ((c >> 3) & 3);
    gA[i] = A + (size_t)(m0 + row) * K + k4 * 8;
    gB[i] = B + (size_t)(n0 + row) * K + k4 * 8;
  }

  const int e = wr * 128 + l15;
  const int f = wc * 64 + l15;
  const unsigned cA0 = ((unsigned)(e >> 1) << 7) + ((e & 1) << 6) + ((l4 ^ ((e >> 1) & 3)) << 4);
  const unsigned cB0 = 16384u + ((unsigned)(f >> 1) << 7) + ((f & 1) << 6) + ((l4 ^ ((f >> 1) & 3)) << 4);
  const char* ldsc = (const char*)lds;

  f32x4 acc[8][4];
#pragma unroll
  for (int i = 0; i < 8; i++)
#pragma unroll
    for (int j = 0; j < 4; j++) acc[i][j] = zero4();

  const int NT = K >> 5;

#pragma unroll
  for (int pt = 0; pt < 2; pt++) {
    unsigned short* db = lds + pt * 16384;
#pragma unroll
    for (int i = 0; i < 2; i++) {
      load_lds16(gA[i] + pt * 32, db + (i * 512 + w * 64) * 8);
      load_lds16(gB[i] + pt * 32, db + ((i + 2) * 512 + w * 64) * 8);
    }
  }
  asm volatile("s_waitcnt vmcnt(4)" ::: "memory");  // tile 0 landed
  __builtin_amdgcn_sched_barrier(0);
  __builtin_amdgcn_s_barrier();
  __builtin_amdgcn_sched_barrier(0);

  int bcur = 0, bstg = 2;
  for (int t = 0; t < NT; ++t) {
    if (t + 2 < NT) {
      unsigned short* db = lds + bstg * 16384;
      const int kt = (t + 2) * 32;
#pragma unroll
      for (int i = 0; i < 2; i++) {
        load_lds16(gA[i] + kt, db + (i * 512 + w * 64) * 8);
        load_lds16(gB[i] + kt, db + ((i + 2) * 512 + w * 64) * 8);
      }
    }
    const unsigned bufb = (unsigned)bcur * 32768u;
    const short8* pA = (const short8*)(ldsc + bufb + cA0);
    const short8* pB = (const short8*)(ldsc + bufb + cB0);
    short8 af[8], bfr[4];
#pragma unroll
    for (int mt = 0; mt < 8; mt++) af[mt] = pA[mt * 64];
#pragma unroll
    for (int nt = 0; nt < 4; nt++) bfr[nt] = pB[nt * 64];

    __builtin_amdgcn_s_setprio(1);
#pragma unroll
    for (int mt = 0; mt < 8; mt++)
#pragma unroll
      for (int nt = 0; nt < 4; nt++)
        acc[mt][nt] = __builtin_amdgcn_mfma_f32_16x16x32_bf16(af[mt], bfr[nt], acc[mt][nt], 0, 0, 0);
    __builtin_amdgcn_s_setprio(0);

    if (t + 1 < NT) {
      if (t + 2 < NT) asm volatile("s_waitcnt vmcnt(4)" ::: "memory");
      else            asm volatile("s_waitcnt vmcnt(0)" ::: "memory");
      __builtin_amdgcn_sched_barrier(0);
      __builtin_amdgcn_s_barrier();
      __builtin_amdgcn_sched_barrier(0);
    }
    bcur = (bcur == 2) ? 0 : bcur + 1;
    bstg = (bstg == 2) ? 0 : bstg + 1;
  }

#pragma unroll
  for (int nt = 0; nt < 4; nt++) {
    const int col = n0 + wc * 64 + nt * 16 + l15;
    const float bvv = bias[col];
#pragma unroll
    for (int mt = 0; mt < 8; mt++) {
      const int row = m0 + wr * 128 + mt * 16 + l4 * 4;
#pragma unroll
      for (int j = 0; j < 4; j++)
        C[(size_t)(row + j) * N + col] = (acc[mt][nt][j] + bvv) * cscale;
    }
  }
}

// C[M][N] = (A[M][K] @ B[N][K]^T + bias) * cscale, A and B bf16 in global.
// m97 structure: 128x128 tile, BK=32, LINEAR LDS, global_load_lds(16B).
template<bool C_BF16>
__global__ __launch_bounds__(256)
void gemm_bb(const unsigned short* __restrict__ A,
             const unsigned short* __restrict__ B,
             const float* __restrict__ bias, float cscale, void* __restrict__ C_,
             int M, int N, int K)
{
  __shared__ unsigned short As[4096];  // [128][32] linear
  __shared__ unsigned short Bs[4096];
  const int t = threadIdx.x;
  const int lane = t & 63, w = t >> 6;
  const int wm = w >> 1, wn = w & 1;
  const int l15 = lane & 15, l4 = lane >> 4;
  const int m0 = blockIdx.y * 128, n0 = blockIdx.x * 128;

  const int srow = w * 32 + (lane >> 2);
  const int scol = (lane & 3) * 8;
  const unsigned short* Ap = A + (size_t)(m0 + srow) * K + scol;
  const unsigned short* Bp = B + (size_t)(n0 + srow) * K + scol;
  unsigned short* AsW = &As[w * 1024];
  unsigned short* BsW = &Bs[w * 1024];

  f32x4 acc[4][4];
#pragma unroll
  for (int i = 0; i < 4; i++)
#pragma unroll
    for (int j = 0; j < 4; j++) acc[i][j] = zero4();

  for (int k0 = 0; k0 < K; k0 += 32) {
    if (k0) __syncthreads();
    load_lds16(Ap + k0, AsW);
    load_lds16(Ap + k0 + (size_t)16 * K, AsW + 512);
    load_lds16(Bp + k0, BsW);
    load_lds16(Bp + k0 + (size_t)16 * K, BsW + 512);
    __syncthreads();

    short8 af[4], bf[4];
#pragma unroll
    for (int mt = 0; mt < 4; mt++)
      af[mt] = *(const short8*)&As[(wm * 64 + mt * 16 + l15) * 32 + l4 * 8];
#pragma unroll
    for (int nt = 0; nt < 4; nt++)
      bf[nt] = *(const short8*)&Bs[(wn * 64 + nt * 16 + l15) * 32 + l4 * 8];
#pragma unroll
    for (int mt = 0; mt < 4; mt++)
#pragma unroll
      for (int nt = 0; nt < 4; nt++)
        acc[mt][nt] = __builtin_amdgcn_mfma_f32_16x16x32_bf16(af[mt], bf[nt], acc[mt][nt], 0, 0, 0);
  }

#pragma unroll
  for (int nt = 0; nt < 4; nt++) {
    const int col = n0 + wn * 64 + nt * 16 + l15;
    const float bvv = bias[col];
#pragma unroll
    for (int mt = 0; mt < 4; mt++) {
#pragma unroll
      for (int j = 0; j < 4; j++) {
        const int row = m0 + wm * 64 + mt * 16 + l4 * 4 + j;
        const float val = (acc[mt][nt][j] + bvv) * cscale;
        if constexpr (C_BF16)
          ((unsigned short*)C_)[(size_t)row * N + col] = f2bf(val);
        else
          ((float*)C_)[(size_t)row * N + col] = val;
      }
    }
  }
}

// Fused K+V projection, 4-way split-K, bf16 operands + global_load_lds.
__global__ __launch_bounds__(256)
void gemm_splitk_bb(const unsigned short* __restrict__ Sb,
                    const unsigned short* __restrict__ Vb,
                    const unsigned short* __restrict__ Wkb,
                    const unsigned short* __restrict__ Wvb,
                    float* __restrict__ Pt)
{
  __shared__ unsigned short As[4096];
  __shared__ unsigned short Bs[4096];
  const int t = threadIdx.x;
  const int lane = t & 63, w = t >> 6;
  const int wm = w >> 1, wn = w & 1;
  const int l15 = lane & 15, l4 = lane >> 4;
  const int m0 = blockIdx.y * 128, n0 = blockIdx.x * 128;
  const int split = blockIdx.z & 3;
  const int tensor = blockIdx.z >> 2;
  const unsigned short* A = tensor ? Vb : Sb;
  const unsigned short* B = tensor ? Wvb : Wkb;
  const int kb = split * 1024;

  const int srow = w * 32 + (lane >> 2);
  const int scol = (lane & 3) * 8;
  const unsigned short* Ap = A + (size_t)(m0 + srow) * 4096 + kb + scol;
  const unsigned short* Bp = B + (size_t)(n0 + srow) * 4096 + kb + scol;
  unsigned short* AsW = &As[w * 1024];
  unsigned short* BsW = &Bs[w * 1024];

  f32x4 acc[4][4];
#pragma unroll
  for (int i = 0; i < 4; i++)
#pragma unroll
    for (int j = 0; j < 4; j++) acc[i][j] = zero4();

  for (int k0 = 0; k0 < 1024; k0 += 32) {
    if (k0) __syncthreads();
    load_lds16(Ap + k0, AsW);
    load_lds16(Ap + k0 + (size_t)16 * 4096, AsW + 512);
    load_lds16(Bp + k0, BsW);
    load_lds16(Bp + k0 + (size_t)16 * 4096, BsW + 512);
    __syncthreads();

    short8 af[4], bf[4];
#pragma unroll
    for (int mt = 0; mt < 4; mt++)
      af[mt] = *(const short8*)&As[(wm * 64 + mt * 16 + l15) * 32 + l4 * 8];
#pragma unroll
    for (int nt = 0; nt < 4; nt++)
      bf[nt] = *(const short8*)&Bs[(wn * 64 + nt * 16 + l15) * 32 + l4 * 8];
#pragma unroll
    for (int mt = 0; mt < 4; mt++)
#pragma unroll
      for (int nt = 0; nt < 4; nt++)
        acc[mt][nt] = __builtin_amdgcn_mfma_f32_16x16x32_bf16(af[mt], bf[nt], acc[mt][nt], 0, 0, 0);
  }

  if (tensor == 0) {
    float* C = Pt + (size_t)split * 1048576;  // [1024][1024] row-major
#pragma unroll
    for (int nt = 0; nt < 4; nt++) {
      const int col = n0 + wn * 64 + nt * 16 + l15;
#pragma unroll
      for (int mt = 0; mt < 4; mt++) {
#pragma unroll
        for (int j = 0; j < 4; j++) {
          const int row = m0 + wm * 64 + mt * 16 + l4 * 4 + j;
          C[(size_t)row * 1024 + col] = acc[mt][nt][j];
        }
      }
    }
  } else {
    float* C = Pt + 4194304 + (size_t)split * 1048576;  // [1024 col][1024 row]
#pragma unroll
    for (int nt = 0; nt < 4; nt++) {
      const int col = n0 + wn * 64 + nt * 16 + l15;
#pragma unroll
      for (int mt = 0; mt < 4; mt++) {
        const int row0 = m0 + wm * 64 + mt * 16 + l4 * 4;
        *(f32x4*)&C[(size_t)col * 1024 + row0] = acc[mt][nt];
      }
    }
  }
}

// Reduce split-K partials + bias. Blocks 0..999: K rows; 1000..2023: V^T.
__global__ __launch_bounds__(256)
void reduce_kv2(const float* __restrict__ Pt, const float* __restrict__ bk,
                const float* __restrict__ bv, unsigned short* __restrict__ Kb,
                unsigned short* __restrict__ Vt)
{
  const int bid = blockIdx.x;
  const int t = threadIdx.x;
  if (bid < 1000) {
    const int v4 = bid * 256 + t;
    const float* base = Pt + (size_t)v4 * 4;
    f32x4 s = *(const f32x4*)(base);
#pragma unroll
    for (int sp = 1; sp < 4; sp++) {
      f32x4 p = *(const f32x4*)(base + (size_t)sp * 1048576);
      s[0] += p[0]; s[1] += p[1]; s[2] += p[2]; s[3] += p[3];
    }
    const int col0 = (v4 * 4) & 1023;
    f32x4 bb = *(const f32x4*)(bk + col0);
    short4v o;
#pragma unroll
    for (int j = 0; j < 4; j++) o[j] = (short)f2bf(s[j] + bb[j]);
    *(short4v*)(Kb + (size_t)v4 * 4) = o;
  } else {
    const int v4 = (bid - 1000) * 256 + t;
    const float* base = Pt + 4194304 + (size_t)v4 * 4;
    f32x4 s = *(const f32x4*)(base);
#pragma unroll
    for (int sp = 1; sp < 4; sp++) {
      f32x4 p = *(const f32x4*)(base + (size_t)sp * 1048576);
      s[0] += p[0]; s[1] += p[1]; s[2] += p[2]; s[3] += p[3];
    }
    const int n = (v4 * 4) >> 10;
    const float bb = bv[n];
    short4v o;
#pragma unroll
    for (int j = 0; j < 4; j++) o[j] = (short)f2bf(s[j] + bb);
    *(short4v*)(Vt + (size_t)v4 * 4) = o;
  }
}

// Fallback reg-staging GEMM (fp32/bf16 A, fp32 B) - used only if ws is small.
template<bool A_BF16, bool C_BF16, bool C_T>
__global__ __launch_bounds__(256)
void gemm_bt(const void* __restrict__ A_, const float* __restrict__ B,
             const float* __restrict__ bias, float cscale, void* __restrict__ C_,
             int M, int N, int K)
{
  __shared__ unsigned short As[128][40];
  __shared__ unsigned short Bs[128][40];
  const int t = threadIdx.x;
  const int lane = t & 63, w = t >> 6;
  const int wm = w >> 1, wn = w & 1;
  const int l15 = lane & 15, l4 = lane >> 4;
  const int m0 = blockIdx.y * 128, n0 = blockIdx.x * 128;
  const int srow = t >> 1, scol = (t & 1) * 16;

  f32x4 acc[4][4];
#pragma unroll
  for (int i = 0; i < 4; i++)
#pragma unroll
    for (int j = 0; j < 4; j++) acc[i][j] = zero4();

  const int am = m0 + srow;
  const int bn = n0 + srow;

  for (int k0 = 0; k0 < K; k0 += 32) {
    short8 av0, av1, bv0, bv1;
    if constexpr (A_BF16) {
      const unsigned short* A = (const unsigned short*)A_;
      if (am < M) {
        const unsigned short* p = A + (size_t)am * K + k0 + scol;
        av0 = *(const short8*)p;
        av1 = *(const short8*)(p + 8);
      } else { av0 = zero8(); av1 = zero8(); }
    } else {
      const float* A = (const float*)A_;
      if (am < M) {
        const float* p = A + (size_t)am * K + k0 + scol;
        f32x4 x0 = *(const f32x4*)(p);
        f32x4 x1 = *(const f32x4*)(p + 4);
        f32x4 x2 = *(const f32x4*)(p + 8);
        f32x4 x3 = *(const f32x4*)(p + 12);
#pragma unroll
        for (int i = 0; i < 4; i++) {
          av0[i]     = (short)f2bf(x0[i]);
          av0[4 + i] = (short)f2bf(x1[i]);
          av1[i]     = (short)f2bf(x2[i]);
          av1[4 + i] = (short)f2bf(x3[i]);
        }
      } else { av0 = zero8(); av1 = zero8(); }
    }
    {
      const float* p = B + (size_t)bn * K + k0 + scol;
      f32x4 x0 = *(const f32x4*)(p);
      f32x4 x1 = *(const f32x4*)(p + 4);
      f32x4 x2 = *(const f32x4*)(p + 8);
      f32x4 x3 = *(const f32x4*)(p + 12);
#pragma unroll
      for (int i = 0; i < 4; i++) {
        bv0[i]     = (short)f2bf(x0[i]);
        bv0[4 + i] = (short)f2bf(x1[i]);
        bv1[i]     = (short)f2bf(x2[i]);
        bv1[4 + i] = (short)f2bf(x3[i]);
      }
    }
    __syncthreads();
    *(short8*)&As[srow][scol]     = av0;
    *(short8*)&As[srow][scol + 8] = av1;
    *(short8*)&Bs[srow][scol]     = bv0;
    *(short8*)&Bs[srow][scol + 8] = bv1;
    __syncthreads();

    short8 af[4], bf[4];
#pragma unroll
    for (int mt = 0; mt < 4; mt++)
      af[mt] = *(const short8*)&As[wm * 64 + mt * 16 + l15][l4 * 8];
#pragma unroll
    for (int nt = 0; nt < 4; nt++)
      bf[nt] = *(const short8*)&Bs[wn * 64 + nt * 16 + l15][l4 * 8];
#pragma unroll
    for (int mt = 0; mt < 4; mt++)
#pragma unroll
      for (int nt = 0; nt < 4; nt++)
        acc[mt][nt] = __builtin_amdgcn_mfma_f32_16x16x32_bf16(af[mt], bf[nt], acc[mt][nt], 0, 0, 0);
  }

#pragma unroll
  for (int nt = 0; nt < 4; nt++) {
    const int col = n0 + wn * 64 + nt * 16 + l15;
    const float bvv = bias[col];
#pragma unroll
    for (int mt = 0; mt < 4; mt++) {
#pragma unroll
      for (int j = 0; j < 4; j++) {
        const int row = m0 + wm * 64 + mt * 16 + l4 * 4 + j;
        if (row < M) {
          float val = (acc[mt][nt][j] + bvv) * cscale;
          if constexpr (C_T)
            ((unsigned short*)C_)[(size_t)col * 1024 + row] = f2bf(val);
          else if constexpr (C_BF16)
            ((unsigned short*)C_)[(size_t)row * N + col] = f2bf(val);
          else
            ((float*)C_)[(size_t)row * N + col] = val;
        }
      }
    }
  }
}

// -------- LDS-staged flash attention, 16 q-rows/wave (R11) --------
// 1024 blocks (h = blockIdx&7 -> XCD locality), 4 waves x 16 rows each,
// K/V tiles double-buffered in LDS (shared by 4 waves), 4 blocks/CU.
// Swapped QK^T + swapped PV (lane-local softmax), exp2 domain, defer-max.
__global__ __launch_bounds__(256, 4)
void attn_fused6(const unsigned short* __restrict__ Q,
                 const unsigned short* __restrict__ Kb,
                 const unsigned short* __restrict__ Vt,
                 unsigned short* __restrict__ Ob)
{
  __shared__ unsigned short Ks[2][32][136];
  __shared__ unsigned short Vs[2][128][40];

  const int t = threadIdx.x;
  const int lane = t & 63, w = t >> 6;
  const int g = lane >> 4, q = lane & 15;
  const int h = blockIdx.x & 7;          // head -> XCD round-robin
  const int bq = blockIdx.x >> 3;        // 0..127
  const int b = bq >> 4, qt = bq & 15;
  const int qrow0 = b * 1024 + qt * 64 + w * 16;

  const unsigned short* Kh = Kb + h * 128;
  const unsigned short* Vh = Vt + (size_t)h * 128 * 1024;

  // Q fragment (B operand): col = q -> query row qrow0+q (scale pre-folded)
  short8 qf[4];
  {
    const unsigned short* qp = Q + (size_t)(qrow0 + q) * 1024 + h * 128;
#pragma unroll
    for (int kk = 0; kk < 4; kk++)
      qf[kk] = *(const short8*)(qp + kk * 32 + g * 8);
  }

  f32x4 o[8];
#pragma unroll
  for (int et = 0; et < 8; et++) o[et] = zero4();
  float m_s = -__builtin_inff(), l_s = 0.f;

  const int krow = t >> 3, kcol = (t & 7) * 16;   // K: [32 s][128 e]
  const int vrow = t >> 1, vcol = (t & 1) * 16;   // V^T: [128 e][32 s]

  // prologue: stage tile 0 into buf 0
  {
    const unsigned short* kp = Kh + (size_t)min(krow, 999) * 1024 + kcol;
    short8 ka0 = *(const short8*)kp, ka1 = *(const short8*)(kp + 8);
    const unsigned short* vp = Vh + (size_t)vrow * 1024 + vcol;
    short8 va0 = *(const short8*)vp, va1 = *(const short8*)(vp + 8);
    *(short8*)&Ks[0][krow][kcol]     = ka0;
    *(short8*)&Ks[0][krow][kcol + 8] = ka1;
    *(short8*)&Vs[0][vrow][vcol]     = va0;
    *(short8*)&Vs[0][vrow][vcol + 8] = va1;
  }
  __syncthreads();

  int cur = 0;
  for (int tile = 0; tile < 32; ++tile) {
    const int s0 = tile * 32;
    const bool last = (s0 == 992);

    // prefetch next tile into registers (issue before compute)
    const int s0n = last ? 992 : s0 + 32;
    const unsigned short* kp = Kh + (size_t)min(s0n + krow, 999) * 1024 + kcol;
    short8 ka0 = *(const short8*)kp, ka1 = *(const short8*)(kp + 8);
    const unsigned short* vp = Vh + (size_t)vrow * 1024 + s0n + vcol;
    short8 va0 = *(const short8*)vp, va1 = *(const short8*)(vp + 8);

    // QK^T from LDS buf[cur]: st = mfma(K, Q), 8 MFMAs
    short8 kf[2][4];
#pragma unroll
    for (int sc = 0; sc < 2; sc++)
#pragma unroll
      for (int kk = 0; kk < 4; kk++)
        kf[sc][kk] = *(const short8*)&Ks[cur][sc * 16 + q][kk * 32 + g * 8];

    f32x4 st[2];
    __builtin_amdgcn_s_setprio(1);
#pragma unroll
    for (int sc = 0; sc < 2; sc++) {
      st[sc] = zero4();
#pragma unroll
      for (int kk = 0; kk < 4; kk++)
        st[sc] = __builtin_amdgcn_mfma_f32_16x16x32_bf16(kf[sc][kk], qf[kk], st[sc], 0, 0, 0);
    }
    __builtin_amdgcn_s_setprio(0);

    // V^T fragments (A operand of PV)
    short8 vf[8];
#pragma unroll
    for (int et = 0; et < 8; et++)
      vf[et] = *(const short8*)&Vs[cur][et * 16 + q][g * 8];

    // online softmax (lane holds 8 s-values for its q-row), exp2 domain
    float a[8];
#pragma unroll
    for (int sc = 0; sc < 2; sc++)
#pragma unroll
      for (int j = 0; j < 4; j++) {
        float v = st[sc][j];
        if (last) {
          const int sl = s0 + sc * 16 + 4 * g + j;
          v = (sl < 1000) ? v : -__builtin_inff();
        }
        a[sc * 4 + j] = v;
      }
    float pmax = fmaxf(fmaxf(fmaxf(a[0], a[1]), fmaxf(a[2], a[3])),
                       fmaxf(fmaxf(a[4], a[5]), fmaxf(a[6], a[7])));
    pmax = fmaxf(pmax, __shfl_xor(pmax, 16));
    pmax = fmaxf(pmax, __shfl_xor(pmax, 32));
    if (!__all(pmax - m_s <= 11.54f)) {  // defer-max (log2 domain)
      const float mn = fmaxf(m_s, pmax);
      const float alpha = exp2f(m_s - mn);  // lane-local (o col = q)
      m_s = mn;
      l_s *= alpha;
#pragma unroll
      for (int et = 0; et < 8; et++)
#pragma unroll
        for (int j = 0; j < 4; j++) o[et][j] *= alpha;
    }
    float e8[8];
#pragma unroll
    for (int k = 0; k < 8; k++) e8[k] = exp2f(a[k] - m_s);
    float rs = ((e8[0] + e8[1]) + (e8[2] + e8[3])) + ((e8[4] + e8[5]) + (e8[6] + e8[7]));
    rs += __shfl_xor(rs, 16);
    rs += __shfl_xor(rs, 32);
    l_s += rs;

    // gather P into B-fragment: lane(g,q) needs P[8g..8g+7][q]
    int D0, D1, D2, D3;
    asm("v_cvt_pk_bf16_f32 %0, %1, %2" : "=v"(D0) : "v"(e8[0]), "v"(e8[1]));
    asm("v_cvt_pk_bf16_f32 %0, %1, %2" : "=v"(D1) : "v"(e8[2]), "v"(e8[3]));
    asm("v_cvt_pk_bf16_f32 %0, %1, %2" : "=v"(D2) : "v"(e8[4]), "v"(e8[5]));
    asm("v_cvt_pk_bf16_f32 %0, %1, %2" : "=v"(D3) : "v"(e8[6]), "v"(e8[7]));
    const int sA = q + ((g & 1) << 5);
    const int sB = sA + 16;
    const int a0 = __shfl(D0, sA), a1 = __shfl(D1, sA);
    const int a2 = __shfl(D2, sA), a3 = __shfl(D3, sA);
    const int b0 = __shfl(D0, sB), b1 = __shfl(D1, sB);
    const int b2 = __shfl(D2, sB), b3 = __shfl(D3, sB);
    const bool hi = (g >= 2);
    int4v pi;
    pi[0] = hi ? a2 : a0;
    pi[1] = hi ? a3 : a1;
    pi[2] = hi ? b2 : b0;
    pi[3] = hi ? b3 : b1;
    const short8 pf = __builtin_bit_cast(short8, pi);

    // PV: o[et] holds O[e = et*16+4g+j][q], 8 MFMAs
    __builtin_amdgcn_s_setprio(1);
#pragma unroll
    for (int et = 0; et < 8; et++)
      o[et] = __builtin_amdgcn_mfma_f32_16x16x32_bf16(vf[et], pf, o[et], 0, 0, 0);
    __builtin_amdgcn_s_setprio(0);

    // write prefetched tile into buf[cur^1], one barrier per tile
    *(short8*)&Ks[cur ^ 1][krow][kcol]     = ka0;
    *(short8*)&Ks[cur ^ 1][krow][kcol + 8] = ka1;
    *(short8*)&Vs[cur ^ 1][vrow][vcol]     = va0;
    *(short8*)&Vs[cur ^ 1][vrow][vcol + 8] = va1;
    __syncthreads();
    cur ^= 1;
  }

  // epilogue: inv lane-local; 8B packed stores
  const float inv = 1.0f / l_s;
  unsigned short* op = Ob + (size_t)(qrow0 + q) * 1024 + h * 128;
#pragma unroll
  for (int et = 0; et < 8; et++) {
    short4v o4;
#pragma unroll
    for (int j = 0; j < 4; j++) o4[j] = (short)f2bf(o[et][j] * inv);
    *(short4v*)(op + et * 16 + 4 * g) = o4;
  }
}

extern "C" void kernel_launch(void* const* d_in, const int* in_sizes, int n_in,
                              void* d_out, int out_size, void* d_ws, size_t ws_size,
                              hipStream_t stream) {
  const float* target = (const float*)d_in[0];   // [8192,1024]
  const float* source = (const float*)d_in[1];   // [1000,4096]
  const float* value  = (const float*)d_in[2];   // [1000,4096]
  const float* Wq = (const float*)d_in[3];       // [1024,1024]
  const float* bq = (const float*)d_in[4];
  const float* Wk = (const float*)d_in[5];       // [1024,4096]
  const float* bk = (const float*)d_in[6];
  const float* Wv = (const float*)d_in[7];       // [1024,4096]
  const float* bv = (const float*)d_in[8];
  const float* Wo = (const float*)d_in[9];       // [4096,1024]
  const float* bo = (const float*)d_in[10];
  float* out = (float*)d_out;

  // 1/sqrt(128) * log2(e): softmax runs in exp2 domain.
  const float SCALE = 0.12751743f;

  char* ws = (char*)d_ws;
  // ws layout (48,185,344 B): see R10 comment. d_out scratch holds Pt +
  // Wkb/Wvb (fully overwritten by final GEMM).
  unsigned short* Sb  = (unsigned short*)(ws);
  unsigned short* Vb  = (unsigned short*)(ws + 8388608);
  unsigned short* Qb  = (unsigned short*)(ws);
  unsigned short* Kb  = (unsigned short*)(ws + 16777216);
  unsigned short* Vt  = (unsigned short*)(ws + 18825216);
  unsigned short* Tb  = (unsigned short*)(ws + 20922368);
  unsigned short* Ab  = (unsigned short*)(ws + 20922368);
  unsigned short* Wqb = (unsigned short*)(ws + 37699584);
  unsigned short* Wob = (unsigned short*)(ws + 39796736);
  float* Pt = (float*)d_out;
  unsigned short* Wkb = (unsigned short*)((char*)d_out + 33554432);
  unsigned short* Wvb = (unsigned short*)((char*)d_out + 41943040);
  const size_t WS_NEED = 48185344;

  dim3 blk(256);
  if (ws_size >= WS_NEED) {
    // 1. convert target/Wq/Wo -> ws; source/value (padded)/Wk/Wv -> bf16
    cvt3_bf16<<<dim3(6656), blk, 0, stream>>>(
        target, Tb, 8192 * 1024, Wq, Wqb, 1024 * 1024, Wo, Wob, 4096 * 1024);
    cvt_kv<<<dim3(8192), blk, 0, stream>>>(
        source, value, Wk, Wv, Sb, Vb, Wkb, Wvb);
    // 2. fused K+V projection, 4-way split-K, global_load_lds staging
    gemm_splitk_bb<<<dim3(8, 8, 8), blk, 0, stream>>>(Sb, Vb, Wkb, Wvb, Pt);
    reduce_kv2<<<dim3(2024), blk, 0, stream>>>(Pt, bk, bv, Kb, Vt);
    // 3. Q = (target @ Wq^T + bq) * scale*log2e  [8192,1024] bf16
    gemm_bb<true><<<dim3(8, 64), blk, 0, stream>>>(
        Tb, Wqb, bq, SCALE, (void*)Qb, 8192, 1024, 1024);
    // 4. fused cross-attention -> Ab (1024 blocks, 16 rows/wave, LDS dbuf)
    attn_fused6<<<dim3(1024), blk, 0, stream>>>(Qb, Kb, Vt, Ab);
    // 5. out = Ab @ Wo^T + bo  [8192,4096] fp32 (R7 counted-vmcnt gemm256)
    gemm256<<<dim3(512), dim3(512), 0, stream>>>(
        Ab, Wob, bo, 1.0f, out, 8192, 4096, 1024);
  } else {
    // Fallback: reg-staging everywhere.
    gemm_bt<false, true, false><<<dim3(8, 64), blk, 0, stream>>>(
        (const void*)target, Wq, bq, SCALE, (void*)Qb, 8192, 1024, 1024);
    gemm_bt<false, true, false><<<dim3(8, 8), blk, 0, stream>>>(
        (const void*)source, Wk, bk, 1.0f, (void*)Kb, 1000, 1024, 4096);
    gemm_bt<false, true, true><<<dim3(8, 8), blk, 0, stream>>>(
        (const void*)value, Wv, bv, 1.0f, (void*)Vt, 1000, 1024, 4096);
    attn_fused6<<<dim3(1024), blk, 0, stream>>>(Qb, Kb, Vt, Ab);
    gemm_bt<true, false, false><<<dim3(32, 64), blk, 0, stream>>>(
        (const void*)Ab, Wo, bo, 1.0f, (void*)out, 8192, 4096, 1024);
  }
}

// Round 12
// 245.727 us; speedup vs baseline: 1.0726x; 1.0726x over previous
//
#include <hip/hip_runtime.h>
#include <hip/hip_bf16.h>

// EnhancedReprogrammingLayer: Q/K/V projections (bf16 MFMA), fused flash
// cross-attention over S=1000 prototypes, output projection to 4096.
// B=8, L=1024, H=8, E=128, D_MODEL=1024, D_LLM=4096, dk=1024.
//
// R1: split-K K/V proj. R2: LDS-free attn. R3: gemm_bb. R4/R5/R9/R11:
//     attention restructures all lost to the R6 dbuf body -> fused4 is the
//     keeper. R6: LDS-staged dbuf attn. R7: gemm256 counted-vmcnt 85.9us.
//     R8 FAILED (phase barriers). R10: split-K on global_load_lds (251us).
// R12: gemm256 prefetch depth 2->3: vmcnt(4) waited on loads issued only
//      ~700cyc earlier (< HBM ~900cyc latency, m126) with 1 block/CU and no
//      cross-block overlap. 4 LDS buffers (128KB), steady-state vmcnt(8),
//      prologue stages 3 tiles, tail drains 8->4->0. Attn = fused4 (R10).

typedef __attribute__((ext_vector_type(8))) short short8;
typedef __attribute__((ext_vector_type(4))) short short4v;
typedef __attribute__((ext_vector_type(4))) float f32x4;
typedef __attribute__((ext_vector_type(4))) int int4v;

#define DEVINL static __device__ __forceinline__

DEVINL unsigned short f2bf(float f) {
  union { float f; unsigned u; } v; v.f = f;
  unsigned r = v.u + 0x7FFFu + ((v.u >> 16) & 1u);
  return (unsigned short)(r >> 16);
}

DEVINL f32x4 zero4() { f32x4 z; z[0] = 0.f; z[1] = 0.f; z[2] = 0.f; z[3] = 0.f; return z; }
DEVINL short8 zero8() { short8 z; z[0]=0; z[1]=0; z[2]=0; z[3]=0; z[4]=0; z[5]=0; z[6]=0; z[7]=0; return z; }

DEVINL void load_lds16(const unsigned short* g, unsigned short* l) {
  __builtin_amdgcn_global_load_lds(
      (const __attribute__((address_space(1))) void*)g,
      (__attribute__((address_space(3))) void*)l, 16, 0, 0);
}

// Bulk fp32 -> bf16 conversion for 3 buffers (8 elems/thread).
__global__ __launch_bounds__(256)
void cvt3_bf16(const float* __restrict__ s0, unsigned short* __restrict__ d0, int n0,
               const float* __restrict__ s1, unsigned short* __restrict__ d1, int n1,
               const float* __restrict__ s2, unsigned short* __restrict__ d2, int n2)
{
  int idx = (blockIdx.x * 256 + threadIdx.x) * 8;
  const float* s; unsigned short* d; int rel = idx;
  if (rel < n0) { s = s0; d = d0; }
  else {
    rel -= n0;
    if (rel < n1) { s = s1; d = d1; }
    else { rel -= n1; if (rel >= n2) return; s = s2; d = d2; }
  }
  f32x4 x0 = *(const f32x4*)(s + rel);
  f32x4 x1 = *(const f32x4*)(s + rel + 4);
  short8 o;
#pragma unroll
  for (int j = 0; j < 4; j++) { o[j] = (short)f2bf(x0[j]); o[4 + j] = (short)f2bf(x1[j]); }
  *(short8*)(d + rel) = o;
}

// Convert source/value (1000x4096, zero-padded to 1024 rows) and Wk/Wv
// (1024x4096) to bf16. 4 segments x 4,194,304 elems, 2048 blocks each.
__global__ __launch_bounds__(256)
void cvt_kv(const float* __restrict__ src, const float* __restrict__ val,
            const float* __restrict__ wk, const float* __restrict__ wv,
            unsigned short* __restrict__ Sb, unsigned short* __restrict__ Vb,
            unsigned short* __restrict__ Wkb, unsigned short* __restrict__ Wvb)
{
  const int seg = blockIdx.x >> 11;  // 2048 blocks per segment
  const int e = (((blockIdx.x & 2047) * 256) + threadIdx.x) * 8;
  const float* s;
  unsigned short* d;
  bool pad = false;
  if (seg == 0)      { s = src; d = Sb;  pad = (e >> 12) >= 1000; }
  else if (seg == 1) { s = val; d = Vb;  pad = (e >> 12) >= 1000; }
  else if (seg == 2) { s = wk;  d = Wkb; }
  else               { s = wv;  d = Wvb; }
  short8 o;
  if (pad) {
    o = zero8();
  } else {
    f32x4 x0 = *(const f32x4*)(s + e);
    f32x4 x1 = *(const f32x4*)(s + e + 4);
#pragma unroll
    for (int j = 0; j < 4; j++) { o[j] = (short)f2bf(x0[j]); o[4 + j] = (short)f2bf(x1[j]); }
  }
  *(short8*)(d + e) = o;
}

// ---------------- gemm256: 256x256 tile, BK=32, counted-vmcnt, depth-3 ----
// C[M][N] fp32 = (A[M][K] @ B[N][K]^T + bias) * cscale. A,B bf16.
// 8 waves (2Mx4N), per-wave 128x64 output. LDS: 4 buffers x 32KB = 128KB.
// Chunk (16B) layout: c <-> row=2*(c>>3)+((c>>2)&1), k4=(c&3)^((c>>3)&3)
// (bijective, 0 bank conflicts verified R7).
// Pipeline: stage t+3 -> ds_read t -> MFMA -> vmcnt(8) -> s_barrier.
// Prefetch distance 3 K-steps (~2100cyc) > HBM miss latency (~900cyc).
__global__ __launch_bounds__(512, 2)
void gemm256(const unsigned short* __restrict__ A,
             const unsigned short* __restrict__ B,
             const float* __restrict__ bias, float cscale,
             float* __restrict__ C, int M, int N, int K)
{
  __shared__ unsigned short lds[65536];  // 128 KB
  const int tid = threadIdx.x;
  const int lane = tid & 63, w = tid >> 6;
  const int wr = w >> 2, wc = w & 3;
  const int l15 = lane & 15, l4 = lane >> 4;

  const int nwg = gridDim.x;
  const int q8 = nwg >> 3;
  const int swz = (blockIdx.x & 7) * q8 + (blockIdx.x >> 3);
  const int nbx = N >> 8;
  const int bx = swz % nbx, by = swz / nbx;
  const int m0 = by << 8, n0 = bx << 8;

  const unsigned short* gA[2];
  const unsigned short* gB[2];
#pragma unroll
  for (int i = 0; i < 2; i++) {
    const int c = i * 512 + tid;
    const int row = 2 * (c >> 3) + ((c >> 2) & 1);
    const int k4 = (c & 3) ^ ((c >> 3) & 3);
    gA[i] = A + (size_t)(m0 + row) * K + k4 * 8;
    gB[i] = B + (size_t)(n0 + row) * K + k4 * 8;
  }

  const int e = wr * 128 + l15;
  const int f = wc * 64 + l15;
  const unsigned cA0 = ((unsigned)(e >> 1) << 7) + ((e & 1) << 6) + ((l4 ^ ((e >> 1) & 3)) << 4);
  const unsigned cB0 = 16384u + ((unsigned)(f >> 1) << 7) + ((f & 1) << 6) + ((l4 ^ ((f >> 1) & 3)) << 4);
  const char* ldsc = (const char*)lds;

  f32x4 acc[8][4];
#pragma unroll
  for (int i = 0; i < 8; i++)
#pragma unroll
    for (int j = 0; j < 4; j++) acc[i][j] = zero4();

  const int NT = K >> 5;  // requires NT >= 3 (K >= 96); here K=1024

  // prologue: stage tiles 0,1,2 into buffers 0,1,2 (12 loads/thread)
#pragma unroll
  for (int pt = 0; pt < 3; pt++) {
    unsigned short* db = lds + pt * 16384;
#pragma unroll
    for (int i = 0; i < 2; i++) {
      load_lds16(gA[i] + pt * 32, db + (i * 512 + w * 64) * 8);
      load_lds16(gB[i] + pt * 32, db + ((i + 2) * 512 + w * 64) * 8);
    }
  }
  asm volatile("s_waitcnt vmcnt(8)" ::: "memory");  // tile 0 landed
  __builtin_amdgcn_sched_barrier(0);
  __builtin_amdgcn_s_barrier();
  __builtin_amdgcn_sched_barrier(0);

  int bcur = 0, bstg = 3;
  for (int t = 0; t < NT; ++t) {
    // issue stage of tile t+3 into buffer bstg = (t-1)&3 (consumed at t-1,
    // all waves past that iteration's barrier -> safe DMA target)
    if (t + 3 < NT) {
      unsigned short* db = lds + bstg * 16384;
      const int kt = (t + 3) * 32;
#pragma unroll
      for (int i = 0; i < 2; i++) {
        load_lds16(gA[i] + kt, db + (i * 512 + w * 64) * 8);
        load_lds16(gB[i] + kt, db + ((i + 2) * 512 + w * 64) * 8);
      }
    }
    const unsigned bufb = (unsigned)bcur * 32768u;
    const short8* pA = (const short8*)(ldsc + bufb + cA0);
    const short8* pB = (const short8*)(ldsc + bufb + cB0);
    short8 af[8], bfr[4];
#pragma unroll
    for (int mt = 0; mt < 8; mt++) af[mt] = pA[mt * 64];
#pragma unroll
    for (int nt = 0; nt < 4; nt++) bfr[nt] = pB[nt * 64];

    __builtin_amdgcn_s_setprio(1);
#pragma unroll
    for (int mt = 0; mt < 8; mt++)
#pragma unroll
      for (int nt = 0; nt < 4; nt++)
        acc[mt][nt] = __builtin_amdgcn_mfma_f32_16x16x32_bf16(af[mt], bfr[nt], acc[mt][nt], 0, 0, 0);
    __builtin_amdgcn_s_setprio(0);

    if (t + 1 < NT) {
      // wait until tile t+1 landed; keep t+2/t+3 in flight (FIFO, m135)
      if (t + 3 < NT)      asm volatile("s_waitcnt vmcnt(8)" ::: "memory");
      else if (t + 2 < NT) asm volatile("s_waitcnt vmcnt(4)" ::: "memory");
      else                 asm volatile("s_waitcnt vmcnt(0)" ::: "memory");
      __builtin_amdgcn_sched_barrier(0);
      __builtin_amdgcn_s_barrier();
      __builtin_amdgcn_sched_barrier(0);
    }
    bcur = (bcur + 1) & 3;
    bstg = (bstg + 1) & 3;
  }

#pragma unroll
  for (int nt = 0; nt < 4; nt++) {
    const int col = n0 + wc * 64 + nt * 16 + l15;
    const float bvv = bias[col];
#pragma unroll
    for (int mt = 0; mt < 8; mt++) {
      const int row = m0 + wr * 128 + mt * 16 + l4 * 4;
#pragma unroll
      for (int j = 0; j < 4; j++)
        C[(size_t)(row + j) * N + col] = (acc[mt][nt][j] + bvv) * cscale;
    }
  }
}

// C[M][N] = (A[M][K] @ B[N][K]^T + bias) * cscale, A and B bf16 in global.
// m97 structure: 128x128 tile, BK=32, LINEAR LDS, global_load_lds(16B).
template<bool C_BF16>
__global__ __launch_bounds__(256)
void gemm_bb(const unsigned short* __restrict__ A,
             const unsigned short* __restrict__ B,
             const float* __restrict__ bias, float cscale, void* __restrict__ C_,
             int M, int N, int K)
{
  __shared__ unsigned short As[4096];  // [128][32] linear
  __shared__ unsigned short Bs[4096];
  const int t = threadIdx.x;
  const int lane = t & 63, w = t >> 6;
  const int wm = w >> 1, wn = w & 1;
  const int l15 = lane & 15, l4 = lane >> 4;
  const int m0 = blockIdx.y * 128, n0 = blockIdx.x * 128;

  const int srow = w * 32 + (lane >> 2);
  const int scol = (lane & 3) * 8;
  const unsigned short* Ap = A + (size_t)(m0 + srow) * K + scol;
  const unsigned short* Bp = B + (size_t)(n0 + srow) * K + scol;
  unsigned short* AsW = &As[w * 1024];
  unsigned short* BsW = &Bs[w * 1024];

  f32x4 acc[4][4];
#pragma unroll
  for (int i = 0; i < 4; i++)
#pragma unroll
    for (int j = 0; j < 4; j++) acc[i][j] = zero4();

  for (int k0 = 0; k0 < K; k0 += 32) {
    if (k0) __syncthreads();
    load_lds16(Ap + k0, AsW);
    load_lds16(Ap + k0 + (size_t)16 * K, AsW + 512);
    load_lds16(Bp + k0, BsW);
    load_lds16(Bp + k0 + (size_t)16 * K, BsW + 512);
    __syncthreads();

    short8 af[4], bf[4];
#pragma unroll
    for (int mt = 0; mt < 4; mt++)
      af[mt] = *(const short8*)&As[(wm * 64 + mt * 16 + l15) * 32 + l4 * 8];
#pragma unroll
    for (int nt = 0; nt < 4; nt++)
      bf[nt] = *(const short8*)&Bs[(wn * 64 + nt * 16 + l15) * 32 + l4 * 8];
#pragma unroll
    for (int mt = 0; mt < 4; mt++)
#pragma unroll
      for (int nt = 0; nt < 4; nt++)
        acc[mt][nt] = __builtin_amdgcn_mfma_f32_16x16x32_bf16(af[mt], bf[nt], acc[mt][nt], 0, 0, 0);
  }

#pragma unroll
  for (int nt = 0; nt < 4; nt++) {
    const int col = n0 + wn * 64 + nt * 16 + l15;
    const float bvv = bias[col];
#pragma unroll
    for (int mt = 0; mt < 4; mt++) {
#pragma unroll
      for (int j = 0; j < 4; j++) {
        const int row = m0 + wm * 64 + mt * 16 + l4 * 4 + j;
        const float val = (acc[mt][nt][j] + bvv) * cscale;
        if constexpr (C_BF16)
          ((unsigned short*)C_)[(size_t)row * N + col] = f2bf(val);
        else
          ((float*)C_)[(size_t)row * N + col] = val;
      }
    }
  }
}

// Fused K+V projection, 4-way split-K, bf16 operands + global_load_lds.
__global__ __launch_bounds__(256)
void gemm_splitk_bb(const unsigned short* __restrict__ Sb,
                    const unsigned short* __restrict__ Vb,
                    const unsigned short* __restrict__ Wkb,
                    const unsigned short* __restrict__ Wvb,
                    float* __restrict__ Pt)
{
  __shared__ unsigned short As[4096];
  __shared__ unsigned short Bs[4096];
  const int t = threadIdx.x;
  const int lane = t & 63, w = t >> 6;
  const int wm = w >> 1, wn = w & 1;
  const int l15 = lane & 15, l4 = lane >> 4;
  const int m0 = blockIdx.y * 128, n0 = blockIdx.x * 128;
  const int split = blockIdx.z & 3;
  const int tensor = blockIdx.z >> 2;
  const unsigned short* A = tensor ? Vb : Sb;
  const unsigned short* B = tensor ? Wvb : Wkb;
  const int kb = split * 1024;

  const int srow = w * 32 + (lane >> 2);
  const int scol = (lane & 3) * 8;
  const unsigned short* Ap = A + (size_t)(m0 + srow) * 4096 + kb + scol;
  const unsigned short* Bp = B + (size_t)(n0 + srow) * 4096 + kb + scol;
  unsigned short* AsW = &As[w * 1024];
  unsigned short* BsW = &Bs[w * 1024];

  f32x4 acc[4][4];
#pragma unroll
  for (int i = 0; i < 4; i++)
#pragma unroll
    for (int j = 0; j < 4; j++) acc[i][j] = zero4();

  for (int k0 = 0; k0 < 1024; k0 += 32) {
    if (k0) __syncthreads();
    load_lds16(Ap + k0, AsW);
    load_lds16(Ap + k0 + (size_t)16 * 4096, AsW + 512);
    load_lds16(Bp + k0, BsW);
    load_lds16(Bp + k0 + (size_t)16 * 4096, BsW + 512);
    __syncthreads();

    short8 af[4], bf[4];
#pragma unroll
    for (int mt = 0; mt < 4; mt++)
      af[mt] = *(const short8*)&As[(wm * 64 + mt * 16 + l15) * 32 + l4 * 8];
#pragma unroll
    for (int nt = 0; nt < 4; nt++)
      bf[nt] = *(const short8*)&Bs[(wn * 64 + nt * 16 + l15) * 32 + l4 * 8];
#pragma unroll
    for (int mt = 0; mt < 4; mt++)
#pragma unroll
      for (int nt = 0; nt < 4; nt++)
        acc[mt][nt] = __builtin_amdgcn_mfma_f32_16x16x32_bf16(af[mt], bf[nt], acc[mt][nt], 0, 0, 0);
  }

  if (tensor == 0) {
    float* C = Pt + (size_t)split * 1048576;  // [1024][1024] row-major
#pragma unroll
    for (int nt = 0; nt < 4; nt++) {
      const int col = n0 + wn * 64 + nt * 16 + l15;
#pragma unroll
      for (int mt = 0; mt < 4; mt++) {
#pragma unroll
        for (int j = 0; j < 4; j++) {
          const int row = m0 + wm * 64 + mt * 16 + l4 * 4 + j;
          C[(size_t)row * 1024 + col] = acc[mt][nt][j];
        }
      }
    }
  } else {
    float* C = Pt + 4194304 + (size_t)split * 1048576;  // [1024 col][1024 row]
#pragma unroll
    for (int nt = 0; nt < 4; nt++) {
      const int col = n0 + wn * 64 + nt * 16 + l15;
#pragma unroll
      for (int mt = 0; mt < 4; mt++) {
        const int row0 = m0 + wm * 64 + mt * 16 + l4 * 4;
        *(f32x4*)&C[(size_t)col * 1024 + row0] = acc[mt][nt];
      }
    }
  }
}

// Reduce split-K partials + bias. Blocks 0..999: K rows; 1000..2023: V^T.
__global__ __launch_bounds__(256)
void reduce_kv2(const float* __restrict__ Pt, const float* __restrict__ bk,
                const float* __restrict__ bv, unsigned short* __restrict__ Kb,
                unsigned short* __restrict__ Vt)
{
  const int bid = blockIdx.x;
  const int t = threadIdx.x;
  if (bid < 1000) {
    const int v4 = bid * 256 + t;
    const float* base = Pt + (size_t)v4 * 4;
    f32x4 s = *(const f32x4*)(base);
#pragma unroll
    for (int sp = 1; sp < 4; sp++) {
      f32x4 p = *(const f32x4*)(base + (size_t)sp * 1048576);
      s[0] += p[0]; s[1] += p[1]; s[2] += p[2]; s[3] += p[3];
    }
    const int col0 = (v4 * 4) & 1023;
    f32x4 bb = *(const f32x4*)(bk + col0);
    short4v o;
#pragma unroll
    for (int j = 0; j < 4; j++) o[j] = (short)f2bf(s[j] + bb[j]);
    *(short4v*)(Kb + (size_t)v4 * 4) = o;
  } else {
    const int v4 = (bid - 1000) * 256 + t;
    const float* base = Pt + 4194304 + (size_t)v4 * 4;
    f32x4 s = *(const f32x4*)(base);
#pragma unroll
    for (int sp = 1; sp < 4; sp++) {
      f32x4 p = *(const f32x4*)(base + (size_t)sp * 1048576);
      s[0] += p[0]; s[1] += p[1]; s[2] += p[2]; s[3] += p[3];
    }
    const int n = (v4 * 4) >> 10;
    const float bb = bv[n];
    short4v o;
#pragma unroll
    for (int j = 0; j < 4; j++) o[j] = (short)f2bf(s[j] + bb);
    *(short4v*)(Vt + (size_t)v4 * 4) = o;
  }
}

// Fallback reg-staging GEMM (fp32/bf16 A, fp32 B) - used only if ws is small.
template<bool A_BF16, bool C_BF16, bool C_T>
__global__ __launch_bounds__(256)
void gemm_bt(const void* __restrict__ A_, const float* __restrict__ B,
             const float* __restrict__ bias, float cscale, void* __restrict__ C_,
             int M, int N, int K)
{
  __shared__ unsigned short As[128][40];
  __shared__ unsigned short Bs[128][40];
  const int t = threadIdx.x;
  const int lane = t & 63, w = t >> 6;
  const int wm = w >> 1, wn = w & 1;
  const int l15 = lane & 15, l4 = lane >> 4;
  const int m0 = blockIdx.y * 128, n0 = blockIdx.x * 128;
  const int srow = t >> 1, scol = (t & 1) * 16;

  f32x4 acc[4][4];
#pragma unroll
  for (int i = 0; i < 4; i++)
#pragma unroll
    for (int j = 0; j < 4; j++) acc[i][j] = zero4();

  const int am = m0 + srow;
  const int bn = n0 + srow;

  for (int k0 = 0; k0 < K; k0 += 32) {
    short8 av0, av1, bv0, bv1;
    if constexpr (A_BF16) {
      const unsigned short* A = (const unsigned short*)A_;
      if (am < M) {
        const unsigned short* p = A + (size_t)am * K + k0 + scol;
        av0 = *(const short8*)p;
        av1 = *(const short8*)(p + 8);
      } else { av0 = zero8(); av1 = zero8(); }
    } else {
      const float* A = (const float*)A_;
      if (am < M) {
        const float* p = A + (size_t)am * K + k0 + scol;
        f32x4 x0 = *(const f32x4*)(p);
        f32x4 x1 = *(const f32x4*)(p + 4);
        f32x4 x2 = *(const f32x4*)(p + 8);
        f32x4 x3 = *(const f32x4*)(p + 12);
#pragma unroll
        for (int i = 0; i < 4; i++) {
          av0[i]     = (short)f2bf(x0[i]);
          av0[4 + i] = (short)f2bf(x1[i]);
          av1[i]     = (short)f2bf(x2[i]);
          av1[4 + i] = (short)f2bf(x3[i]);
        }
      } else { av0 = zero8(); av1 = zero8(); }
    }
    {
      const float* p = B + (size_t)bn * K + k0 + scol;
      f32x4 x0 = *(const f32x4*)(p);
      f32x4 x1 = *(const f32x4*)(p + 4);
      f32x4 x2 = *(const f32x4*)(p + 8);
      f32x4 x3 = *(const f32x4*)(p + 12);
#pragma unroll
      for (int i = 0; i < 4; i++) {
        bv0[i]     = (short)f2bf(x0[i]);
        bv0[4 + i] = (short)f2bf(x1[i]);
        bv1[i]     = (short)f2bf(x2[i]);
        bv1[4 + i] = (short)f2bf(x3[i]);
      }
    }
    __syncthreads();
    *(short8*)&As[srow][scol]     = av0;
    *(short8*)&As[srow][scol + 8] = av1;
    *(short8*)&Bs[srow][scol]     = bv0;
    *(short8*)&Bs[srow][scol + 8] = bv1;
    __syncthreads();

    short8 af[4], bf[4];
#pragma unroll
    for (int mt = 0; mt < 4; mt++)
      af[mt] = *(const short8*)&As[wm * 64 + mt * 16 + l15][l4 * 8];
#pragma unroll
    for (int nt = 0; nt < 4; nt++)
      bf[nt] = *(const short8*)&Bs[wn * 64 + nt * 16 + l15][l4 * 8];
#pragma unroll
    for (int mt = 0; mt < 4; mt++)
#pragma unroll
      for (int nt = 0; nt < 4; nt++)
        acc[mt][nt] = __builtin_amdgcn_mfma_f32_16x16x32_bf16(af[mt], bf[nt], acc[mt][nt], 0, 0, 0);
  }

#pragma unroll
  for (int nt = 0; nt < 4; nt++) {
    const int col = n0 + wn * 64 + nt * 16 + l15;
    const float bvv = bias[col];
#pragma unroll
    for (int mt = 0; mt < 4; mt++) {
#pragma unroll
      for (int j = 0; j < 4; j++) {
        const int row = m0 + wm * 64 + mt * 16 + l4 * 4 + j;
        if (row < M) {
          float val = (acc[mt][nt][j] + bvv) * cscale;
          if constexpr (C_T)
            ((unsigned short*)C_)[(size_t)col * 1024 + row] = f2bf(val);
          else if constexpr (C_BF16)
            ((unsigned short*)C_)[(size_t)row * N + col] = f2bf(val);
          else
            ((float*)C_)[(size_t)row * N + col] = val;
        }
      }
    }
  }
}

// ---------------- LDS-staged fused flash attention (R6 body, exp2) --------
__global__ __launch_bounds__(256, 2)
void attn_fused4(const unsigned short* __restrict__ Q,
                 const unsigned short* __restrict__ Kb,
                 const unsigned short* __restrict__ Vt,
                 unsigned short* __restrict__ Ob)
{
  __shared__ unsigned short Ks[2][32][136];
  __shared__ unsigned short Vs[2][128][40];

  const int t = threadIdx.x;
  const int lane = t & 63, w = t >> 6;
  const int g = lane >> 4, q = lane & 15;
  const int qt = blockIdx.x & 7, bh = blockIdx.x >> 3;
  const int b = bh >> 3, h = bh & 7;
  const int qrow0 = b * 1024 + qt * 128 + w * 32;

  const unsigned short* Kh = Kb + h * 128;
  const unsigned short* Vh = Vt + (size_t)h * 128 * 1024;

  short8 qf[2][4];
#pragma unroll
  for (int qn = 0; qn < 2; qn++) {
    const unsigned short* qp = Q + (size_t)(qrow0 + qn * 16 + q) * 1024 + h * 128;
#pragma unroll
    for (int kk = 0; kk < 4; kk++)
      qf[qn][kk] = *(const short8*)(qp + kk * 32 + g * 8);
  }

  f32x4 o[2][8];
#pragma unroll
  for (int qn = 0; qn < 2; qn++)
#pragma unroll
    for (int et = 0; et < 8; et++) o[qn][et] = zero4();
  float m_s[2] = {-__builtin_inff(), -__builtin_inff()};
  float l_s[2] = {0.f, 0.f};

  const int krow = t >> 3, kcol = (t & 7) * 16;   // K: [32 s][128 e]
  const int vrow = t >> 1, vcol = (t & 1) * 16;   // V^T: [128 e][32 s]

  {
    const unsigned short* kp = Kh + (size_t)min(krow, 999) * 1024 + kcol;
    short8 ka0 = *(const short8*)kp, ka1 = *(const short8*)(kp + 8);
    const unsigned short* vp = Vh + (size_t)vrow * 1024 + vcol;
    short8 va0 = *(const short8*)vp, va1 = *(const short8*)(vp + 8);
    *(short8*)&Ks[0][krow][kcol]     = ka0;
    *(short8*)&Ks[0][krow][kcol + 8] = ka1;
    *(short8*)&Vs[0][vrow][vcol]     = va0;
    *(short8*)&Vs[0][vrow][vcol + 8] = va1;
  }
  __syncthreads();

  int cur = 0;
  for (int tile = 0; tile < 32; ++tile) {
    const int s0 = tile * 32;
    const bool last = (s0 == 992);

    const int s0n = last ? 992 : s0 + 32;
    const unsigned short* kp = Kh + (size_t)min(s0n + krow, 999) * 1024 + kcol;
    short8 ka0 = *(const short8*)kp, ka1 = *(const short8*)(kp + 8);
    const unsigned short* vp = Vh + (size_t)vrow * 1024 + s0n + vcol;
    short8 va0 = *(const short8*)vp, va1 = *(const short8*)(vp + 8);

    short8 kf[2][4];
#pragma unroll
    for (int sc = 0; sc < 2; sc++)
#pragma unroll
      for (int kk = 0; kk < 4; kk++)
        kf[sc][kk] = *(const short8*)&Ks[cur][sc * 16 + q][kk * 32 + g * 8];

    f32x4 st[2][2];
    __builtin_amdgcn_s_setprio(1);
#pragma unroll
    for (int qn = 0; qn < 2; qn++)
#pragma unroll
      for (int sc = 0; sc < 2; sc++) {
        st[qn][sc] = zero4();
#pragma unroll
        for (int kk = 0; kk < 4; kk++)
          st[qn][sc] = __builtin_amdgcn_mfma_f32_16x16x32_bf16(kf[sc][kk], qf[qn][kk], st[qn][sc], 0, 0, 0);
      }
    __builtin_amdgcn_s_setprio(0);

    short8 vf[8];
#pragma unroll
    for (int et = 0; et < 8; et++)
      vf[et] = *(const short8*)&Vs[cur][et * 16 + q][g * 8];

#pragma unroll
    for (int qn = 0; qn < 2; qn++) {
      float a[8];
#pragma unroll
      for (int sc = 0; sc < 2; sc++)
#pragma unroll
        for (int j = 0; j < 4; j++) {
          float v = st[qn][sc][j];
          if (last) {
            const int sl = s0 + sc * 16 + 4 * g + j;
            v = (sl < 1000) ? v : -__builtin_inff();
          }
          a[sc * 4 + j] = v;
        }
      float pmax = fmaxf(fmaxf(fmaxf(a[0], a[1]), fmaxf(a[2], a[3])),
                         fmaxf(fmaxf(a[4], a[5]), fmaxf(a[6], a[7])));
      pmax = fmaxf(pmax, __shfl_xor(pmax, 16));
      pmax = fmaxf(pmax, __shfl_xor(pmax, 32));
      if (!__all(pmax - m_s[qn] <= 11.54f)) {  // defer-max (log2 domain)
        const float mn = fmaxf(m_s[qn], pmax);
        const float alpha = exp2f(m_s[qn] - mn);  // lane-local (o col = q)
        m_s[qn] = mn;
        l_s[qn] *= alpha;
#pragma unroll
        for (int et = 0; et < 8; et++)
#pragma unroll
          for (int j = 0; j < 4; j++) o[qn][et][j] *= alpha;
      }
      float e8[8];
#pragma unroll
      for (int k = 0; k < 8; k++) e8[k] = exp2f(a[k] - m_s[qn]);
      float rs = ((e8[0] + e8[1]) + (e8[2] + e8[3])) + ((e8[4] + e8[5]) + (e8[6] + e8[7]));
      rs += __shfl_xor(rs, 16);
      rs += __shfl_xor(rs, 32);
      l_s[qn] += rs;

      int D0, D1, D2, D3;
      asm("v_cvt_pk_bf16_f32 %0, %1, %2" : "=v"(D0) : "v"(e8[0]), "v"(e8[1]));
      asm("v_cvt_pk_bf16_f32 %0, %1, %2" : "=v"(D1) : "v"(e8[2]), "v"(e8[3]));
      asm("v_cvt_pk_bf16_f32 %0, %1, %2" : "=v"(D2) : "v"(e8[4]), "v"(e8[5]));
      asm("v_cvt_pk_bf16_f32 %0, %1, %2" : "=v"(D3) : "v"(e8[6]), "v"(e8[7]));
      const int sA = q + ((g & 1) << 5);
      const int sB = sA + 16;
      const int a0 = __shfl(D0, sA), a1 = __shfl(D1, sA);
      const int a2 = __shfl(D2, sA), a3 = __shfl(D3, sA);
      const int b0 = __shfl(D0, sB), b1 = __shfl(D1, sB);
      const int b2 = __shfl(D2, sB), b3 = __shfl(D3, sB);
      const bool hi = (g >= 2);
      int4v pi;
      pi[0] = hi ? a2 : a0;
      pi[1] = hi ? a3 : a1;
      pi[2] = hi ? b2 : b0;
      pi[3] = hi ? b3 : b1;
      const short8 pf = __builtin_bit_cast(short8, pi);

      __builtin_amdgcn_s_setprio(1);
#pragma unroll
      for (int et = 0; et < 8; et++)
        o[qn][et] = __builtin_amdgcn_mfma_f32_16x16x32_bf16(vf[et], pf, o[qn][et], 0, 0, 0);
      __builtin_amdgcn_s_setprio(0);
    }

    *(short8*)&Ks[cur ^ 1][krow][kcol]     = ka0;
    *(short8*)&Ks[cur ^ 1][krow][kcol + 8] = ka1;
    *(short8*)&Vs[cur ^ 1][vrow][vcol]     = va0;
    *(short8*)&Vs[cur ^ 1][vrow][vcol + 8] = va1;
    __syncthreads();
    cur ^= 1;
  }

#pragma unroll
  for (int qn = 0; qn < 2; qn++) {
    const float inv = 1.0f / l_s[qn];
    unsigned short* op = Ob + (size_t)(qrow0 + qn * 16 + q) * 1024 + h * 128;
#pragma unroll
    for (int et = 0; et < 8; et++) {
      short4v o4;
#pragma unroll
      for (int j = 0; j < 4; j++) o4[j] = (short)f2bf(o[qn][et][j] * inv);
      *(short4v*)(op + et * 16 + 4 * g) = o4;
    }
  }
}

extern "C" void kernel_launch(void* const* d_in, const int* in_sizes, int n_in,
                              void* d_out, int out_size, void* d_ws, size_t ws_size,
                              hipStream_t stream) {
  const float* target = (const float*)d_in[0];   // [8192,1024]
  const float* source = (const float*)d_in[1];   // [1000,4096]
  const float* value  = (const float*)d_in[2];   // [1000,4096]
  const float* Wq = (const float*)d_in[3];       // [1024,1024]
  const float* bq = (const float*)d_in[4];
  const float* Wk = (const float*)d_in[5];       // [1024,4096]
  const float* bk = (const float*)d_in[6];
  const float* Wv = (const float*)d_in[7];       // [1024,4096]
  const float* bv = (const float*)d_in[8];
  const float* Wo = (const float*)d_in[9];       // [4096,1024]
  const float* bo = (const float*)d_in[10];
  float* out = (float*)d_out;

  // 1/sqrt(128) * log2(e): softmax runs in exp2 domain.
  const float SCALE = 0.12751743f;

  char* ws = (char*)d_ws;
  // ws layout (48,185,344 B): see R10 comment. d_out scratch holds Pt +
  // Wkb/Wvb (fully overwritten by final GEMM).
  unsigned short* Sb  = (unsigned short*)(ws);
  unsigned short* Vb  = (unsigned short*)(ws + 8388608);
  unsigned short* Qb  = (unsigned short*)(ws);
  unsigned short* Kb  = (unsigned short*)(ws + 16777216);
  unsigned short* Vt  = (unsigned short*)(ws + 18825216);
  unsigned short* Tb  = (unsigned short*)(ws + 20922368);
  unsigned short* Ab  = (unsigned short*)(ws + 20922368);
  unsigned short* Wqb = (unsigned short*)(ws + 37699584);
  unsigned short* Wob = (unsigned short*)(ws + 39796736);
  float* Pt = (float*)d_out;
  unsigned short* Wkb = (unsigned short*)((char*)d_out + 33554432);
  unsigned short* Wvb = (unsigned short*)((char*)d_out + 41943040);
  const size_t WS_NEED = 48185344;

  dim3 blk(256);
  if (ws_size >= WS_NEED) {
    // 1. convert target/Wq/Wo -> ws; source/value (padded)/Wk/Wv -> bf16
    cvt3_bf16<<<dim3(6656), blk, 0, stream>>>(
        target, Tb, 8192 * 1024, Wq, Wqb, 1024 * 1024, Wo, Wob, 4096 * 1024);
    cvt_kv<<<dim3(8192), blk, 0, stream>>>(
        source, value, Wk, Wv, Sb, Vb, Wkb, Wvb);
    // 2. fused K+V projection, 4-way split-K, global_load_lds staging
    gemm_splitk_bb<<<dim3(8, 8, 8), blk, 0, stream>>>(Sb, Vb, Wkb, Wvb, Pt);
    reduce_kv2<<<dim3(2024), blk, 0, stream>>>(Pt, bk, bv, Kb, Vt);
    // 3. Q = (target @ Wq^T + bq) * scale*log2e  [8192,1024] bf16
    gemm_bb<true><<<dim3(8, 64), blk, 0, stream>>>(
        Tb, Wqb, bq, SCALE, (void*)Qb, 8192, 1024, 1024);
    // 4. fused cross-attention -> Ab (512 blocks, R6 dbuf body)
    attn_fused4<<<dim3(512), blk, 0, stream>>>(Qb, Kb, Vt, Ab);
    // 5. out = Ab @ Wo^T + bo  [8192,4096] fp32 (depth-3 counted-vmcnt)
    gemm256<<<dim3(512), dim3(512), 0, stream>>>(
        Ab, Wob, bo, 1.0f, out, 8192, 4096, 1024);
  } else {
    // Fallback: reg-staging everywhere.
    gemm_bt<false, true, false><<<dim3(8, 64), blk, 0, stream>>>(
        (const void*)target, Wq, bq, SCALE, (void*)Qb, 8192, 1024, 1024);
    gemm_bt<false, true, false><<<dim3(8, 8), blk, 0, stream>>>(
        (const void*)source, Wk, bk, 1.0f, (void*)Kb, 1000, 1024, 4096);
    gemm_bt<false, true, true><<<dim3(8, 8), blk, 0, stream>>>(
        (const void*)value, Wv, bv, 1.0f, (void*)Vt, 1000, 1024, 4096);
    attn_fused4<<<dim3(512), blk, 0, stream>>>(Qb, Kb, Vt, Ab);
    gemm_bt<true, false, false><<<dim3(32, 64), blk, 0, stream>>>(
        (const void*)Ab, Wo, bo, 1.0f, (void*)out, 8192, 4096, 1024);
  }
}